// Round 16
// baseline (242.649 us; speedup 1.0000x reference)
//
#include <hip/hip_runtime.h>
#include <hip/hip_bf16.h>

#define BB 1024
#define NN 32
#define SUD 8
#define HD 64
#define NCD 4
#define ED 992      // NN*(NN-1)
#define NITER 5

// ---- fp32 weight workspace layout (element offsets into d_ws) ----
#define O_W2AT 0        // 18 x 64   W2aT[su][f] = W2a[f][su]
#define O_B2A  1152     // 64
#define O_W2B  1216     // 32 x 64 (dead, kept for offset stability)
#define O_B2B  3264     // 32
#define O_W2CT 3296     // 32 x 8 (dead)
#define O_B2C  3552     // 8
#define O_WIHT 3560     // 10 x 192 (dead)
#define O_BIH  5480     // 192
#define O_WHHT 5672     // first 3072 floats repurposed: FRAG_WIH bf16 (R24)
#define O_BHH  17960    // 192
#define O_W4T  18152    // R28: W4^T bf16 B-frags (512 slots, K=64, su pad 16)
#define O_B4   18664    // 8
#define O_W3AT 18672    // 8 x 64 (dead since R29: head W3a via MFMA)
#define O_B3A  19184    // 64
#define O_W3BT 19248    // 64 x 32 (dead since R29: head W3b via MFMA)
#define O_B3B  21296    // 32
#define O_W3CT 21328    // 32 x 4
#define O_B3C  21456    // 4
#define O_W1AT 21460    // 3 x 8
#define O_B1A  21484    // 8
#define W_TOTAL 21492
#define O_WIHP 21492    // R29: [0,1024) = W3a^T bf16 frags; [1024,2048) = W3b^T frags
#define W_TOTAL2 25332

// ---- bf16 MFMA fragment region at ws + W_TOTAL2 (bf16 element offsets) ----
#define FRAG_B2   0        // 2048: W2b frags, EVEN/ODD interleaved out-rows
#define FRAG_C    2048     // 512
#define FRAG_WHH  2560     // 12288
#define FRAG_A2P  14848    // 4096: W2a (s1|s2 halves) B-frags, K=8 real
#define FRAG_TOTAL 18944
#define PREP_TOTAL (W_TOTAL2 + FRAG_TOTAL)   // 44276; ws bytes = 139,216

typedef const float* fwp;
typedef __attribute__((ext_vector_type(8))) short short8;
typedef __attribute__((ext_vector_type(4))) float float4v;
typedef __attribute__((ext_vector_type(2))) float float2v;

__device__ __forceinline__ short bf16r(float x) {
  __hip_bfloat16 h = __float2bfloat16(x);
  return __builtin_bit_cast(short, h);
}

__global__ void prep_weights(fwp W2a, fwp b2a, fwp W2b, fwp b2b, fwp W2c, fwp b2c,
                             fwp Wih, fwp bih, fwp Whh, fwp bhh,
                             fwp W3a, fwp b3a, fwp W3b, fwp b3b, fwp W3c, fwp b3c,
                             fwp W4, fwp b4, fwp W1a, fwp b1a, float* __restrict__ ws) {
  int idx = blockIdx.x * 256 + threadIdx.x;
  if (idx >= PREP_TOTAL) return;
  if (idx >= W_TOTAL2) {
    __hip_bfloat16* wbw = (__hip_bfloat16*)(ws + W_TOTAL2);
    int e = idx - W_TOTAL2;
    float v;
    if (e < 2048) {
      // W2b frag, even/odd interleave: h=0 frag -> out row 2*col, h=1 -> 2*col+1
      int j = e & 7, L = (e >> 3) & 63, hs = e >> 9;
      int h = hs >> 1, s = hs & 1;
      v = W2b[(2 * (L & 15) + h) * 64 + s * 32 + ((L >> 4) & 3) * 8 + j];
    } else if (e < 2560) {
      int e2 = e - 2048;
      int j = e2 & 7, L = (e2 >> 3) & 63;
      int su = L & 15, q = L >> 4;
      v = (su < 8) ? W2c[su * 32 + q * 8 + j] : 0.f;
    } else if (e < 14848) {
      int e2 = e - 2560;                 // [0, 12288)
      int j = e2 & 7, L = (e2 >> 3) & 63, nts = e2 >> 9;
      int nt = nts >> 1, s = nts & 1;
      v = Whh[(nt * 16 + (L & 15)) * 64 + s * 32 + ((L >> 4) & 3) * 8 + j];
    } else {
      // W2a B-frags: nt 0..3 = s1 half (su 0..7), nt 4..7 = s2 half (su 8..15)
      int e2 = e - 14848;                // [0, 4096)
      int j = e2 & 7, L = (e2 >> 3) & 63, nt = e2 >> 9;
      int col = L & 15, kq = L >> 4;
      v = 0.f;
      if (kq == 0) v = (nt < 4) ? W2a[(nt * 16 + col) * 18 + j]
                                : W2a[((nt - 4) * 16 + col) * 18 + 8 + j];
    }
    wbw[e] = __float2bfloat16(v);
    return;
  }
  if (idx >= W_TOTAL) {
    // R29: head frags. [0,1024): W3a^T (4 col-tiles, K=8 real pad 32).
    //      [1024,2048): W3b^T (2 col-tiles x 2 K-halves, K=64).
    int p = idx - O_WIHP;
    if (p < 1024) {
      unsigned packed = 0;
#pragma unroll
      for (int h = 0; h < 2; ++h) {
        int e = 2 * p + h;               // [0, 2048)
        int j = e & 7, L = (e >> 3) & 63, ct = e >> 9;
        int col = L & 15, kq = (L >> 4) & 3;
        float vv = (kq == 0) ? W3a[(ct * 16 + col) * 8 + j] : 0.f;
        unsigned us = (unsigned short)bf16r(vv);
        packed |= us << (16 * h);
      }
      ws[idx] = __builtin_bit_cast(float, packed);
    } else if (p < 2048) {
      int p2 = p - 1024;
      unsigned packed = 0;
#pragma unroll
      for (int h = 0; h < 2; ++h) {
        int e = 2 * p2 + h;              // [0, 2048)
        int j = e & 7, L = (e >> 3) & 63, cts = e >> 9;
        int ct = cts >> 1, s = cts & 1;
        float vv = W3b[(ct * 16 + (L & 15)) * 64 + s * 32 + ((L >> 4) & 3) * 8 + j];
        unsigned us = (unsigned short)bf16r(vv);
        packed |= us << (16 * h);
      }
      ws[idx] = __builtin_bit_cast(float, packed);
    } else {
      ws[idx] = 0.f;
    }
    return;
  }
  float v;
  if (idx < O_B2A)       { int p = idx;          int su = p / 64, f = p % 64;   v = W2a[f * 18 + su]; }
  else if (idx < O_W2B)  { v = b2a[idx - O_B2A]; }
  else if (idx < O_B2B)  { v = W2b[idx - O_W2B]; }
  else if (idx < O_W2CT) { v = b2b[idx - O_B2B]; }
  else if (idx < O_B2C)  { int p = idx - O_W2CT; int o = p / 8, su = p % 8;     v = W2c[su * 32 + o]; }
  else if (idx < O_WIHT) { v = b2c[idx - O_B2C]; }
  else if (idx < O_BIH)  { int p = idx - O_WIHT; int k = p / 192, o = p % 192;  v = Wih[o * 10 + k]; }
  else if (idx < O_WHHT) { v = bih[idx - O_BIH]; }
  else if (idx < O_BHH)  {
    int p = idx - O_WHHT;
    if (p < 3072) {
      // FRAG_WIH: B-frags for gin @ Wih^T, K=32 (k<10 real). Two bf16 per slot.
      unsigned packed = 0;
#pragma unroll
      for (int h = 0; h < 2; ++h) {
        int e = 2 * p + h;
        int j = e & 7, L = (e >> 3) & 63, nt = e >> 9;
        int k = ((L >> 4) & 3) * 8 + j;
        float vv = (k < 10) ? Wih[(nt * 16 + (L & 15)) * 10 + k] : 0.f;
        unsigned us = (unsigned short)bf16r(vv);
        packed |= us << (16 * h);
      }
      ws[idx] = __builtin_bit_cast(float, packed);
      return;
    }
    int k = p / 192, o = p % 192;  v = Whh[o * 64 + k];
  }
  else if (idx < O_W4T)  { v = bhh[idx - O_BHH]; }
  else if (idx < O_B4)   {
    // R28: W4^T B-frags bf16-pair packed (K=64 in 2 frags, su pad 16).
    int p = idx - O_W4T;               // [0, 512)
    unsigned packed = 0;
#pragma unroll
    for (int h = 0; h < 2; ++h) {
      int e = 2 * p + h;               // [0, 1024)
      int j = e & 7, L = (e >> 3) & 63, s = e >> 9;
      int su = L & 15;
      int k = s * 32 + ((L >> 4) & 3) * 8 + j;
      float vv = (su < 8) ? W4[su * 64 + k] : 0.f;
      unsigned us = (unsigned short)bf16r(vv);
      packed |= us << (16 * h);
    }
    ws[idx] = __builtin_bit_cast(float, packed);
    return;
  }
  else if (idx < O_W3AT) { v = b4[idx - O_B4]; }
  else if (idx < O_B3A)  { int p = idx - O_W3AT; int k = p / 64, f = p % 64;    v = W3a[f * 8 + k]; }
  else if (idx < O_W3BT) { v = b3a[idx - O_B3A]; }
  else if (idx < O_B3B)  { int p = idx - O_W3BT; int k = p / 32, f = p % 32;    v = W3b[f * 64 + k]; }
  else if (idx < O_W3CT) { v = b3b[idx - O_B3B]; }
  else if (idx < O_B3C)  { int p = idx - O_W3CT; int k = p / 4, c = p % 4;      v = W3c[c * 32 + k]; }
  else if (idx < O_W1AT) { v = b3c[idx - O_B3C]; }
  else if (idx < O_B1A)  { int p = idx - O_W1AT; int c = p / 8, su = p % 8;     v = W1a[su * 3 + c]; }
  else                   { v = b1a[idx - O_B1A]; }
  ws[idx] = v;
}

// Layer-b K-step, parameterized (R21): packed fp32 math, bf16 MFMA pair.
// FH0 -> even out-cols (ACC0), FH1 -> odd out-cols (ACC1).
#define DO_STEP2(AROW, EWV, KOFF, Y0, Y1, W0, W1, FH0, FH1, ACC0, ACC1)        \
  {                                                                            \
    float4v x0 = *(const float4v*)&sA1[(AROW) * 68 + (KOFF)];                  \
    float4v x1 = *(const float4v*)&sA1[(AROW) * 68 + (KOFF) + 4];              \
    float4v z4 = {0.f, 0.f, 0.f, 0.f};                                         \
    float4v t0 = (x0 + Y0) + (EWV) * W0;                                       \
    float4v t1 = (x1 + Y1) + (EWV) * W1;                                       \
    t0 = __builtin_elementwise_max(t0, z4);                                    \
    t1 = __builtin_elementwise_max(t1, z4);                                    \
    short8 ahi;                                                                \
    ahi[0] = bf16r(t0.x); ahi[1] = bf16r(t0.y); ahi[2] = bf16r(t0.z);          \
    ahi[3] = bf16r(t0.w); ahi[4] = bf16r(t1.x); ahi[5] = bf16r(t1.y);          \
    ahi[6] = bf16r(t1.z); ahi[7] = bf16r(t1.w);                                \
    ACC0 = __builtin_amdgcn_mfma_f32_16x16x32_bf16(ahi, FH0, ACC0, 0, 0, 0);   \
    ACC1 = __builtin_amdgcn_mfma_f32_16x16x32_bf16(ahi, FH1, ACC1, 0, 0, 0);   \
  }

#define LAUNDER(v) __asm__ __volatile__("" : "+v"(v))

// (256,4): 4 waves/SIMD = 4 blocks/CU (LDS 38656). R29: head W3a/W3b via MFMA
// (last scalar matmuls; W3c stays scalar). Wave wv: W3a f-cols wv*16..+15 both
// mt; W3b mt=wv>>1, col-tile=wv&1. Frags in dead O_WIHP. Phase-local, kernel
// end, no pressure overlap. Tripwire: test fail / bench > 238.8 / WRITE > 62
// -> revert R28 and declare floor.
__global__ __launch_bounds__(256, 4) void gnn_fused(
    const float* __restrict__ read_gru_in,
    const float* __restrict__ gru_init,
    const float* __restrict__ feat,
    const float* __restrict__ edge_w,
    const float* __restrict__ noise_in,
    const float* __restrict__ xhat,
    const float* __restrict__ vep,
    const int* __restrict__ gnn_iter_p,
    const float* __restrict__ ws,
    const float* __restrict__ W4g,
    float* __restrict__ out)
{
  // spool: edge-phase {sA1, sA2, sM2} only (GRU handoff in registers since R24).
  __shared__ __attribute__((aligned(16))) char spool[23040];
  __shared__ __attribute__((aligned(16))) float sH[NN * 68];
  __shared__ float sNodes[NN * 9];
  __shared__ float sSum[NN * 8];
  __shared__ float sEw[ED];
  __shared__ float sC1[64];
  __shared__ float sWew[64];
  __shared__ float sX[NN];
  __shared__ float sV[NN];

  float* const sA1 = (float*)spool;                             // 8704 B
  float* const sA2 = (float*)(spool + 8704);                    // 8704 B
  __hip_bfloat16* const sM2 = (__hip_bfloat16*)(spool + 17408); // 5632 B

  const int b = blockIdx.x;
  const int t = threadIdx.x;
  const int lane = t & 63;
  const int wv = t >> 6;
  const int quad = lane >> 4;
  const int lm = lane & 15;

  const __hip_bfloat16* wb = (const __hip_bfloat16*)(ws + W_TOTAL2);

  // ---- per-sample inputs ----
  float noi = noise_in[b];
  for (int e = t; e < ED; e += 256) sEw[e] = edge_w[b * ED + e];
  if (t < NN) { sX[t] = xhat[b * NN + t]; sV[t] = vep[b * NN + t]; }
  if (t < 64) {
    sC1[t]  = ws[O_B2A + t] + noi * ws[O_W2AT + 17 * 64 + t];
    sWew[t] = ws[O_W2AT + 16 * 64 + t];
  }
#pragma unroll
  for (int i = 0; i < 8; ++i) {
    int p = t + 256 * i;
    sH[(p >> 6) * 68 + (p & 63)] = gru_init[b * (NN * HD) + p];
  }
  // ---- init_nodes (iteration 0 only) ----
  {
    const int git = gnn_iter_p[0];
    int n = t >> 3, su = t & 7;
    float acc;
    if (git == 0) {
      acc = ws[O_B1A + su];
#pragma unroll
      for (int c = 0; c < 3; ++c)
        acc += ws[O_W1AT + c * 8 + su] * feat[b * (NN * 3) + n * 3 + c];
    } else {
      acc = read_gru_in[b * (NN * SUD) + t];
    }
    sNodes[n * 9 + su] = acc;
  }
  __syncthreads();

  for (int it = 0; it < NITER; ++it) {
    // ---- edge-phase frag loads issued EARLY (hide L2 latency under A1/A2).
    //      Lifetime: here -> end of edge phase; does NOT span GRU phases. ----
    int ive = 0; LAUNDER(ive);
    const float* wsle = ws + ive;
    const __hip_bfloat16* wble = wb + ive;
    short8 fbh00 = *(const short8*)(wble + FRAG_B2 + (0 * 64 + lane) * 8);
    short8 fbh01 = *(const short8*)(wble + FRAG_B2 + (1 * 64 + lane) * 8);
    short8 fbh10 = *(const short8*)(wble + FRAG_B2 + (2 * 64 + lane) * 8);
    short8 fbh11 = *(const short8*)(wble + FRAG_B2 + (3 * 64 + lane) * 8);
    short8 fcf   = *(const short8*)(wble + FRAG_C + lane * 8);
    const float2v b2bv = *(const float2v*)&wsle[O_B2B + 2 * lm];
    const float   b2cl = wsle[O_B2C + lm];

    // ---- A1/A2 node projections via MFMA (K=8 real, zero-padded to 32).
    //      Wave wv computes f-cols [wv*16, wv*16+16) for both halves. ----
    {
      int iva = 0; LAUNDER(iva);
      const __hip_bfloat16* fp = wb + FRAG_A2P + iva;
      short8 aN[2];
#pragma unroll
      for (int mt = 0; mt < 2; ++mt) {
        short8 a = {0, 0, 0, 0, 0, 0, 0, 0};
        if (quad == 0) {
          const float* np = &sNodes[(mt * 16 + lm) * 9];
#pragma unroll
          for (int q = 0; q < 8; ++q) a[q] = bf16r(np[q]);
        }
        aN[mt] = a;
      }
      const int f = wv * 16 + lm;
      const float c1f = sC1[f];
#pragma unroll
      for (int half = 0; half < 2; ++half) {
        short8 bfr = *(const short8*)(fp + ((half * 4 + wv) * 64 + lane) * 8);
#pragma unroll
        for (int mt = 0; mt < 2; ++mt) {
          float4v acc = {0.f, 0.f, 0.f, 0.f};
          acc = __builtin_amdgcn_mfma_f32_16x16x32_bf16(aN[mt], bfr, acc, 0, 0, 0);
#pragma unroll
          for (int r = 0; r < 4; ++r) {
            int node = mt * 16 + quad * 4 + r;
            if (half == 0) sA1[node * 68 + f] = acc[r];
            else           sA2[node * 68 + f] = acc[r] + c1f;
          }
        }
      }
    }
    __syncthreads();

    // ---- edge MLP via MFMA (biases pre-folded into acc inits); tile1 compute
    //      pipelined into tile0's m2 store->read latency window (R21) ----
    {
      int ivz = 0; LAUNDER(ivz);
      __hip_bfloat16* m2w = sM2 + wv * (16 * 44);
      const int kq0 = quad * 8, kq1 = 32 + quad * 8;
      float4v wwA = *(const float4v*)&sWew[ivz + kq0];
      float4v wwB = *(const float4v*)&sWew[ivz + kq0 + 4];
      float4v wwC = *(const float4v*)&sWew[ivz + kq1];
      float4v wwD = *(const float4v*)&sWew[ivz + kq1 + 4];
      const float4v binit0 = {b2bv.x, b2bv.x, b2bv.x, b2bv.x};
      const float4v binit1 = {b2bv.y, b2bv.y, b2bv.y, b2bv.y};
      const float4v cinit  = {b2cl, b2cl, b2cl, b2cl};
      const int kkB = 16 + lm;
      const int kkB2 = (kkB < 31) ? kkB : 0;
      for (int ni = 0; ni < 8; ++ni) {
        const int jj = wv * 8 + ni;
        const int a0 = lm + (lm >= jj ? 1 : 0);
        const int a1 = kkB2 + (kkB2 >= jj ? 1 : 0);
        const float ew0 = sEw[ivz + jj * 31 + lm];
        const float ew1 = (kkB < 31) ? sEw[ivz + jj * 31 + kkB] : 0.f;
        float4v yA = *(const float4v*)&sA2[jj * 68 + kq0];
        float4v yB = *(const float4v*)&sA2[jj * 68 + kq0 + 4];
        float4v yC = *(const float4v*)&sA2[jj * 68 + kq1];
        float4v yD = *(const float4v*)&sA2[jj * 68 + kq1 + 4];
        // tile0 layer-b
        float4v acc00 = binit0;
        float4v acc01 = binit1;
        DO_STEP2(a0, ew0, kq0, yA, yB, wwA, wwB, fbh00, fbh10, acc00, acc01);
        DO_STEP2(a0, ew0, kq1, yC, yD, wwC, wwD, fbh01, fbh11, acc00, acc01);
        // tile0 m2 store
#pragma unroll
        for (int r = 0; r < 4; ++r) {
          float m20 = fmaxf(acc00[r], 0.f);
          float m21 = fmaxf(acc01[r], 0.f);
          ushort2 pp;
          pp.x = (unsigned short)bf16r(m20);
          pp.y = (unsigned short)bf16r(m21);
          *(ushort2*)(m2w + (quad * 4 + r) * 44 + 2 * lm) = pp;
        }
        // tile1 layer-b fills tile0's store->read latency window
        float4v acc10 = binit0;
        float4v acc11 = binit1;
        DO_STEP2(a1, ew1, kq0, yA, yB, wwA, wwB, fbh00, fbh10, acc10, acc11);
        DO_STEP2(a1, ew1, kq1, yC, yD, wwC, wwD, fbh01, fbh11, acc10, acc11);
        __asm__ __volatile__("" ::: "memory");
        // tile0 read + layer-c
        float psum;
        {
          short8 ac = *(const short8*)(m2w + lm * 44 + quad * 8);
          float4v c3 = cinit;
          c3 = __builtin_amdgcn_mfma_f32_16x16x32_bf16(ac, fcf, c3, 0, 0, 0);
          psum  = fmaxf(c3[0], 0.f);
          psum += fmaxf(c3[1], 0.f);
          psum += fmaxf(c3[2], 0.f);
          psum += fmaxf(c3[3], 0.f);
        }
        __asm__ __volatile__("" ::: "memory");
        // tile1 m2 store (after tile0 read)
#pragma unroll
        for (int r = 0; r < 4; ++r) {
          float m20 = fmaxf(acc10[r], 0.f);
          float m21 = fmaxf(acc11[r], 0.f);
          ushort2 pp;
          pp.x = (unsigned short)bf16r(m20);
          pp.y = (unsigned short)bf16r(m21);
          *(ushort2*)(m2w + (quad * 4 + r) * 44 + 2 * lm) = pp;
        }
        __asm__ __volatile__("" ::: "memory");
        // tile1 read + layer-c (kk=31 lane masked at r==3, quad==3)
        {
          short8 ac = *(const short8*)(m2w + lm * 44 + quad * 8);
          float4v c3 = cinit;
          c3 = __builtin_amdgcn_mfma_f32_16x16x32_bf16(ac, fcf, c3, 0, 0, 0);
#pragma unroll
          for (int r = 0; r < 4; ++r) {
            float v = fmaxf(c3[r], 0.f);
            if (r == 3) v = (quad == 3) ? 0.f : v;
            psum += v;
          }
        }
        __asm__ __volatile__("" ::: "memory");
        psum += __shfl_xor(psum, 16);
        psum += __shfl_xor(psum, 32);
        if (lane < 8) sSum[jj * 8 + lane] = psum;
      }
    }
    __syncthreads();

    // ---- GRU fused: gate pre-activations via MFMA, K=64 (H@Whh^T) plus
    //      K=32 gin=[sSum|x|v]@Wih^T. Wave wv owns gate tiles {wv,4+wv,8+wv};
    //      lane (quad,lm) holds node mt*16+quad*4+rr at col c = wv*16+lm
    //      (MFMA C-layout). No sGH round-trip, no GRU2 k-loop (R24). ----
    {
      int ivg = 0; LAUNDER(ivg);
      const __hip_bfloat16* wbl = wb + ivg;
      const __hip_bfloat16* wihf = (const __hip_bfloat16*)(ws + O_WHHT) + ivg;
      short8 aH[2][2];
      short8 aG[2];
#pragma unroll
      for (int mt = 0; mt < 2; ++mt) {
#pragma unroll
        for (int s = 0; s < 2; ++s) {
          const float* hp = &sH[(mt * 16 + lm) * 68 + s * 32 + quad * 8];
          float4v h0 = *(const float4v*)hp;
          float4v h1 = *(const float4v*)(hp + 4);
          short8 a;
          a[0] = bf16r(h0.x); a[1] = bf16r(h0.y); a[2] = bf16r(h0.z); a[3] = bf16r(h0.w);
          a[4] = bf16r(h1.x); a[5] = bf16r(h1.y); a[6] = bf16r(h1.z); a[7] = bf16r(h1.w);
          aH[mt][s] = a;
        }
        // gin A-frag: k = quad*8 + j ; k<8 -> sSum, k=8 -> x, k=9 -> v
        short8 g = {0, 0, 0, 0, 0, 0, 0, 0};
        int nrow = mt * 16 + lm;
        if (quad == 0) {
          float4v s0 = *(const float4v*)&sSum[nrow * 8];
          float4v s1 = *(const float4v*)&sSum[nrow * 8 + 4];
          g[0] = bf16r(s0.x); g[1] = bf16r(s0.y); g[2] = bf16r(s0.z); g[3] = bf16r(s0.w);
          g[4] = bf16r(s1.x); g[5] = bf16r(s1.y); g[6] = bf16r(s1.z); g[7] = bf16r(s1.w);
        } else if (quad == 1) {
          g[0] = bf16r(sX[nrow]);
          g[1] = bf16r(sV[nrow]);
        }
        aG[mt] = g;
      }
      const float4v zz4 = {0.f, 0.f, 0.f, 0.f};
      float4v pr0, pr1, pz0, pz1, phn0, phn1, pin0, pin1;
      {
        // r-gate tile (i+h merged)
        int gnt = wv;
        short8 bh0 = *(const short8*)(wbl + FRAG_WHH + ((gnt * 2 + 0) * 64 + lane) * 8);
        short8 bh1 = *(const short8*)(wbl + FRAG_WHH + ((gnt * 2 + 1) * 64 + lane) * 8);
        short8 bwi = *(const short8*)(wihf + (gnt * 64 + lane) * 8);
        pr0 = __builtin_amdgcn_mfma_f32_16x16x32_bf16(aG[0], bwi, zz4, 0, 0, 0);
        pr0 = __builtin_amdgcn_mfma_f32_16x16x32_bf16(aH[0][0], bh0, pr0, 0, 0, 0);
        pr0 = __builtin_amdgcn_mfma_f32_16x16x32_bf16(aH[0][1], bh1, pr0, 0, 0, 0);
        pr1 = __builtin_amdgcn_mfma_f32_16x16x32_bf16(aG[1], bwi, zz4, 0, 0, 0);
        pr1 = __builtin_amdgcn_mfma_f32_16x16x32_bf16(aH[1][0], bh0, pr1, 0, 0, 0);
        pr1 = __builtin_amdgcn_mfma_f32_16x16x32_bf16(aH[1][1], bh1, pr1, 0, 0, 0);
      }
      {
        // z-gate tile (i+h merged)
        int gnt = 4 + wv;
        short8 bh0 = *(const short8*)(wbl + FRAG_WHH + ((gnt * 2 + 0) * 64 + lane) * 8);
        short8 bh1 = *(const short8*)(wbl + FRAG_WHH + ((gnt * 2 + 1) * 64 + lane) * 8);
        short8 bwi = *(const short8*)(wihf + (gnt * 64 + lane) * 8);
        pz0 = __builtin_amdgcn_mfma_f32_16x16x32_bf16(aG[0], bwi, zz4, 0, 0, 0);
        pz0 = __builtin_amdgcn_mfma_f32_16x16x32_bf16(aH[0][0], bh0, pz0, 0, 0, 0);
        pz0 = __builtin_amdgcn_mfma_f32_16x16x32_bf16(aH[0][1], bh1, pz0, 0, 0, 0);
        pz1 = __builtin_amdgcn_mfma_f32_16x16x32_bf16(aG[1], bwi, zz4, 0, 0, 0);
        pz1 = __builtin_amdgcn_mfma_f32_16x16x32_bf16(aH[1][0], bh0, pz1, 0, 0, 0);
        pz1 = __builtin_amdgcn_mfma_f32_16x16x32_bf16(aH[1][1], bh1, pz1, 0, 0, 0);
      }
      {
        // n-gate tile: i and h kept SEPARATE (reference: tanh(i_n + r*h_n))
        int gnt = 8 + wv;
        short8 bh0 = *(const short8*)(wbl + FRAG_WHH + ((gnt * 2 + 0) * 64 + lane) * 8);
        short8 bh1 = *(const short8*)(wbl + FRAG_WHH + ((gnt * 2 + 1) * 64 + lane) * 8);
        short8 bwi = *(const short8*)(wihf + (gnt * 64 + lane) * 8);
        phn0 = __builtin_amdgcn_mfma_f32_16x16x32_bf16(aH[0][0], bh0, zz4, 0, 0, 0);
        phn0 = __builtin_amdgcn_mfma_f32_16x16x32_bf16(aH[0][1], bh1, phn0, 0, 0, 0);
        phn1 = __builtin_amdgcn_mfma_f32_16x16x32_bf16(aH[1][0], bh0, zz4, 0, 0, 0);
        phn1 = __builtin_amdgcn_mfma_f32_16x16x32_bf16(aH[1][1], bh1, phn1, 0, 0, 0);
        pin0 = __builtin_amdgcn_mfma_f32_16x16x32_bf16(aG[0], bwi, zz4, 0, 0, 0);
        pin1 = __builtin_amdgcn_mfma_f32_16x16x32_bf16(aG[1], bwi, zz4, 0, 0, 0);
      }
      // gates + blend, all register-resident; rcp-based sigmoid/tanh
      const int c = wv * 16 + lm;
      const float br  = ws[O_BIH + c]       + ws[O_BHH + c];
      const float bz  = ws[O_BIH + 64 + c]  + ws[O_BHH + 64 + c];
      const float bni = ws[O_BIH + 128 + c];
      const float bnh = ws[O_BHH + 128 + c];
      float4v hn0, hn1;
#pragma unroll
      for (int mt = 0; mt < 2; ++mt) {
#pragma unroll
        for (int rr = 0; rr < 4; ++rr) {
          int n = mt * 16 + quad * 4 + rr;
          float pre_r = ((mt == 0) ? pr0[rr]  : pr1[rr])  + br;
          float pre_z = ((mt == 0) ? pz0[rr]  : pz1[rr])  + bz;
          float i_n   = ((mt == 0) ? pin0[rr] : pin1[rr]) + bni;
          float h_n   = ((mt == 0) ? phn0[rr] : phn1[rr]) + bnh;
          float er = __expf(-pre_r);
          float r = __builtin_amdgcn_rcpf(1.f + er);
          float ez = __expf(-pre_z);
          float z = __builtin_amdgcn_rcpf(1.f + ez);
          float cd = i_n + r * h_n;
          float e2 = __expf(2.f * cd);
          float th = 1.f - 2.f * __builtin_amdgcn_rcpf(e2 + 1.f);
          float hv = sH[n * 68 + c];
          float hnew = th + z * (hv - th);
          if (mt == 0) hn0[rr] = hnew; else hn1[rr] = hnew;
        }
      }
      __syncthreads();   // all waves' sH reads (aH frags + blend hv) complete
#pragma unroll
      for (int rr = 0; rr < 4; ++rr) {
        sH[(quad * 4 + rr) * 68 + c]      = hn0[rr];
        sH[(16 + quad * 4 + rr) * 68 + c] = hn1[rr];
      }
    }
    __syncthreads();

    // ---- read_gru = W4 @ h + b4 -> sNodes.
    //      it<4 (R28): MFMA path (waves 0/1, mt 0/1); it==4: fp32 path. ----
    if (it < NITER - 1) {
      if (wv < 2) {
        int ivw = 0; LAUNDER(ivw);
        const __hip_bfloat16* w4f = (const __hip_bfloat16*)(ws + O_W4T) + ivw;
        const int mt = wv;
        short8 aW[2];
#pragma unroll
        for (int s = 0; s < 2; ++s) {
          const float* hp = &sH[(mt * 16 + lm) * 68 + s * 32 + quad * 8];
          float4v h0 = *(const float4v*)hp;
          float4v h1 = *(const float4v*)(hp + 4);
          short8 a;
          a[0] = bf16r(h0.x); a[1] = bf16r(h0.y); a[2] = bf16r(h0.z); a[3] = bf16r(h0.w);
          a[4] = bf16r(h1.x); a[5] = bf16r(h1.y); a[6] = bf16r(h1.z); a[7] = bf16r(h1.w);
          aW[s] = a;
        }
        short8 bW0 = *(const short8*)(w4f + (0 * 64 + lane) * 8);
        short8 bW1 = *(const short8*)(w4f + (1 * 64 + lane) * 8);
        const float b4l = (lm < 8) ? ws[O_B4 + lm] : 0.f;
        float4v acc = {b4l, b4l, b4l, b4l};
        acc = __builtin_amdgcn_mfma_f32_16x16x32_bf16(aW[0], bW0, acc, 0, 0, 0);
        acc = __builtin_amdgcn_mfma_f32_16x16x32_bf16(aW[1], bW1, acc, 0, 0, 0);
        if (lm < 8) {
#pragma unroll
          for (int rr = 0; rr < 4; ++rr)
            sNodes[(mt * 16 + quad * 4 + rr) * 9 + lm] = acc[rr];
        }
      }
    } else {
      int ivw = 0; LAUNDER(ivw);
      int n = t >> 3, su = t & 7;
      const float* w4r = W4g + ivw + su * 64;
      float4v acc4 = {0.f, 0.f, 0.f, 0.f};
#pragma unroll
      for (int k = 0; k < 64; k += 4) {
        float4v w = *(const float4v*)&w4r[k];
        float4v h = *(const float4v*)&sH[n * 68 + k];
        acc4 += w * h;
      }
      sNodes[n * 9 + su] = ws[O_B4 + su] + ((acc4.x + acc4.y) + (acc4.z + acc4.w));
    }
    __syncthreads();
  } // iterations

  // ---- head (R29): W3a via MFMA (K=8 pad 32), W3b via MFMA (K=64), W3c scalar ----
  {
    int ivh = 0; LAUNDER(ivh);
    const __hip_bfloat16* w3af = (const __hip_bfloat16*)(ws + O_WIHP) + ivh;
    short8 aN[2];
#pragma unroll
    for (int mt = 0; mt < 2; ++mt) {
      short8 a = {0, 0, 0, 0, 0, 0, 0, 0};
      if (quad == 0) {
        const float* np = &sNodes[(mt * 16 + lm) * 9];
#pragma unroll
        for (int q = 0; q < 8; ++q) a[q] = bf16r(np[q]);
      }
      aN[mt] = a;
    }
    const int f = wv * 16 + lm;
    const float b3af = ws[O_B3A + f];
    short8 bfr = *(const short8*)(w3af + (wv * 64 + lane) * 8);
#pragma unroll
    for (int mt = 0; mt < 2; ++mt) {
      float4v acc = {b3af, b3af, b3af, b3af};
      acc = __builtin_amdgcn_mfma_f32_16x16x32_bf16(aN[mt], bfr, acc, 0, 0, 0);
#pragma unroll
      for (int rr = 0; rr < 4; ++rr)
        sA1[(mt * 16 + quad * 4 + rr) * 68 + f] = acc[rr];
    }
  }
  __syncthreads();
  {
    int ivh = 0; LAUNDER(ivh);
    const __hip_bfloat16* w3bf = (const __hip_bfloat16*)(ws + O_WIHP + 1024) + ivh;
    const int mt = wv >> 1, ct = wv & 1;
    short8 aA[2];
#pragma unroll
    for (int s = 0; s < 2; ++s) {
      const float* ap = &sA1[(mt * 16 + lm) * 68 + s * 32 + quad * 8];
      float4v a0 = *(const float4v*)ap;
      float4v a1 = *(const float4v*)(ap + 4);
      short8 a;
      a[0] = bf16r(a0.x); a[1] = bf16r(a0.y); a[2] = bf16r(a0.z); a[3] = bf16r(a0.w);
      a[4] = bf16r(a1.x); a[5] = bf16r(a1.y); a[6] = bf16r(a1.z); a[7] = bf16r(a1.w);
      aA[s] = a;
    }
    short8 b0 = *(const short8*)(w3bf + ((ct * 2 + 0) * 64 + lane) * 8);
    short8 b1 = *(const short8*)(w3bf + ((ct * 2 + 1) * 64 + lane) * 8);
    const float b3bf = ws[O_B3B + ct * 16 + lm];
    float4v acc = {b3bf, b3bf, b3bf, b3bf};
    acc = __builtin_amdgcn_mfma_f32_16x16x32_bf16(aA[0], b0, acc, 0, 0, 0);
    acc = __builtin_amdgcn_mfma_f32_16x16x32_bf16(aA[1], b1, acc, 0, 0, 0);
#pragma unroll
    for (int rr = 0; rr < 4; ++rr)
      sA2[(mt * 16 + quad * 4 + rr) * 33 + ct * 16 + lm] = acc[rr];
  }
  __syncthreads();
  if (t < 128) {
    int n = t >> 2, c = t & 3;
    float acc = ws[O_B3C + c];
#pragma unroll
    for (int k = 0; k < 32; ++k) acc += ws[O_W3CT + k * 4 + c] * sA2[n * 33 + k];
    out[b * (NN * NCD) + t] = acc;
  }
  out[BB * NN * NCD + b * (NN * SUD) + t] = sNodes[(t >> 3) * 9 + (t & 7)];
#pragma unroll
  for (int i = 0; i < 8; ++i) {
    int p = t + 256 * i;
    out[BB * NN * NCD + BB * NN * SUD + b * (NN * HD) + p] =
        sH[(p >> 6) * 68 + (p & 63)];
  }
}

extern "C" void kernel_launch(void* const* d_in, const int* in_sizes, int n_in,
                              void* d_out, int out_size, void* d_ws, size_t ws_size,
                              hipStream_t stream) {
  typedef const float* F32;
  F32 read_gru = (F32)d_in[0];
  F32 gru_init = (F32)d_in[1];
  F32 feat     = (F32)d_in[2];
  F32 edge_w   = (F32)d_in[3];
  F32 noise    = (F32)d_in[4];
  F32 xh       = (F32)d_in[5];
  F32 vp       = (F32)d_in[6];
  F32 W1a = (F32)d_in[7];  F32 b1a = (F32)d_in[8];
  F32 W2a = (F32)d_in[9];  F32 b2a = (F32)d_in[10];
  F32 W2b = (F32)d_in[11]; F32 b2b = (F32)d_in[12];
  F32 W2c = (F32)d_in[13]; F32 b2c = (F32)d_in[14];
  F32 Wih = (F32)d_in[15]; F32 bih = (F32)d_in[16];
  F32 Whh = (F32)d_in[17]; F32 bhh = (F32)d_in[18];
  F32 W3a = (F32)d_in[19]; F32 b3a = (F32)d_in[20];
  F32 W3b = (F32)d_in[21]; F32 b3b = (F32)d_in[22];
  F32 W3c = (F32)d_in[23]; F32 b3c = (F32)d_in[24];
  F32 W4  = (F32)d_in[25]; F32 b4  = (F32)d_in[26];
  const int* git = (const int*)d_in[27];
  float* ws = (float*)d_ws;   // needs 139,216 B

  prep_weights<<<(PREP_TOTAL + 255) / 256, 256, 0, stream>>>(
      W2a, b2a, W2b, b2b, W2c, b2c, Wih, bih, Whh, bhh,
      W3a, b3a, W3b, b3b, W3c, b3c, W4, b4, W1a, b1a, ws);

  gnn_fused<<<BB, 256, 0, stream>>>(read_gru, gru_init, feat, edge_w, noise,
                                    xh, vp, git, ws, W4, (float*)d_out);
}

// Round 17
// 236.998 us; speedup vs baseline: 1.0238x; 1.0238x over previous
//
#include <hip/hip_runtime.h>
#include <hip/hip_bf16.h>

#define BB 1024
#define NN 32
#define SUD 8
#define HD 64
#define NCD 4
#define ED 992      // NN*(NN-1)
#define NITER 5

// ---- fp32 weight workspace layout (element offsets into d_ws) ----
#define O_W2AT 0        // 18 x 64   W2aT[su][f] = W2a[f][su]
#define O_B2A  1152     // 64
#define O_W2B  1216     // 32 x 64 (dead, kept for offset stability)
#define O_B2B  3264     // 32
#define O_W2CT 3296     // 32 x 8 (dead)
#define O_B2C  3552     // 8
#define O_WIHT 3560     // 10 x 192 (dead)
#define O_BIH  5480     // 192
#define O_WHHT 5672     // first 3072 floats repurposed: FRAG_WIH bf16 (R24)
#define O_BHH  17960    // 192
#define O_W4T  18152    // R28: W4^T bf16 B-frags (512 slots, K=64, su pad 16)
#define O_B4   18664    // 8
#define O_W3AT 18672    // 8 x 64 (dead since R29: head W3a via MFMA)
#define O_B3A  19184    // 64
#define O_W3BT 19248    // 64 x 32 (dead since R29: head W3b via MFMA)
#define O_B3B  21296    // 32
#define O_W3CT 21328    // 32 x 4
#define O_B3C  21456    // 4
#define O_W1AT 21460    // 3 x 8
#define O_B1A  21484    // 8
#define W_TOTAL 21492
#define O_WIHP 21492    // R29: [0,1024) = W3a^T bf16 frags; [1024,2048) = W3b^T frags
#define W_TOTAL2 25332

// ---- bf16 MFMA fragment region at ws + W_TOTAL2 (bf16 element offsets) ----
#define FRAG_B2   0        // 2048: W2b frags, EVEN/ODD interleaved out-rows
#define FRAG_C    2048     // 512
#define FRAG_WHH  2560     // 12288
#define FRAG_A2P  14848    // 4096: W2a (s1|s2 halves) B-frags, K=8 real
#define FRAG_TOTAL 18944
#define PREP_TOTAL (W_TOTAL2 + FRAG_TOTAL)   // 44276; ws bytes = 139,216

typedef const float* fwp;
typedef __attribute__((ext_vector_type(8))) short short8;
typedef __attribute__((ext_vector_type(4))) float float4v;
typedef __attribute__((ext_vector_type(2))) float float2v;

__device__ __forceinline__ short bf16r(float x) {
  __hip_bfloat16 h = __float2bfloat16(x);
  return __builtin_bit_cast(short, h);
}

__global__ void prep_weights(fwp W2a, fwp b2a, fwp W2b, fwp b2b, fwp W2c, fwp b2c,
                             fwp Wih, fwp bih, fwp Whh, fwp bhh,
                             fwp W3a, fwp b3a, fwp W3b, fwp b3b, fwp W3c, fwp b3c,
                             fwp W4, fwp b4, fwp W1a, fwp b1a, float* __restrict__ ws) {
  int idx = blockIdx.x * 256 + threadIdx.x;
  if (idx >= PREP_TOTAL) return;
  if (idx >= W_TOTAL2) {
    __hip_bfloat16* wbw = (__hip_bfloat16*)(ws + W_TOTAL2);
    int e = idx - W_TOTAL2;
    float v;
    if (e < 2048) {
      // W2b frag, even/odd interleave: h=0 frag -> out row 2*col, h=1 -> 2*col+1
      int j = e & 7, L = (e >> 3) & 63, hs = e >> 9;
      int h = hs >> 1, s = hs & 1;
      v = W2b[(2 * (L & 15) + h) * 64 + s * 32 + ((L >> 4) & 3) * 8 + j];
    } else if (e < 2560) {
      int e2 = e - 2048;
      int j = e2 & 7, L = (e2 >> 3) & 63;
      int su = L & 15, q = L >> 4;
      v = (su < 8) ? W2c[su * 32 + q * 8 + j] : 0.f;
    } else if (e < 14848) {
      int e2 = e - 2560;                 // [0, 12288)
      int j = e2 & 7, L = (e2 >> 3) & 63, nts = e2 >> 9;
      int nt = nts >> 1, s = nts & 1;
      v = Whh[(nt * 16 + (L & 15)) * 64 + s * 32 + ((L >> 4) & 3) * 8 + j];
    } else {
      // W2a B-frags: nt 0..3 = s1 half (su 0..7), nt 4..7 = s2 half (su 8..15)
      int e2 = e - 14848;                // [0, 4096)
      int j = e2 & 7, L = (e2 >> 3) & 63, nt = e2 >> 9;
      int col = L & 15, kq = L >> 4;
      v = 0.f;
      if (kq == 0) v = (nt < 4) ? W2a[(nt * 16 + col) * 18 + j]
                                : W2a[((nt - 4) * 16 + col) * 18 + 8 + j];
    }
    wbw[e] = __float2bfloat16(v);
    return;
  }
  if (idx >= W_TOTAL) {
    // R29: head frags. [0,1024): W3a^T (4 col-tiles, K=8 real pad 32).
    //      [1024,2048): W3b^T (2 col-tiles x 2 K-halves, K=64).
    int p = idx - O_WIHP;
    if (p < 1024) {
      unsigned packed = 0;
#pragma unroll
      for (int h = 0; h < 2; ++h) {
        int e = 2 * p + h;               // [0, 2048)
        int j = e & 7, L = (e >> 3) & 63, ct = e >> 9;
        int col = L & 15, kq = (L >> 4) & 3;
        float vv = (kq == 0) ? W3a[(ct * 16 + col) * 8 + j] : 0.f;
        unsigned us = (unsigned short)bf16r(vv);
        packed |= us << (16 * h);
      }
      ws[idx] = __builtin_bit_cast(float, packed);
    } else if (p < 2048) {
      int p2 = p - 1024;
      unsigned packed = 0;
#pragma unroll
      for (int h = 0; h < 2; ++h) {
        int e = 2 * p2 + h;              // [0, 2048)
        int j = e & 7, L = (e >> 3) & 63, cts = e >> 9;
        int ct = cts >> 1, s = cts & 1;
        float vv = W3b[(ct * 16 + (L & 15)) * 64 + s * 32 + ((L >> 4) & 3) * 8 + j];
        unsigned us = (unsigned short)bf16r(vv);
        packed |= us << (16 * h);
      }
      ws[idx] = __builtin_bit_cast(float, packed);
    } else {
      ws[idx] = 0.f;
    }
    return;
  }
  float v;
  if (idx < O_B2A)       { int p = idx;          int su = p / 64, f = p % 64;   v = W2a[f * 18 + su]; }
  else if (idx < O_W2B)  { v = b2a[idx - O_B2A]; }
  else if (idx < O_B2B)  { v = W2b[idx - O_W2B]; }
  else if (idx < O_W2CT) { v = b2b[idx - O_B2B]; }
  else if (idx < O_B2C)  { int p = idx - O_W2CT; int o = p / 8, su = p % 8;     v = W2c[su * 32 + o]; }
  else if (idx < O_WIHT) { v = b2c[idx - O_B2C]; }
  else if (idx < O_BIH)  { int p = idx - O_WIHT; int k = p / 192, o = p % 192;  v = Wih[o * 10 + k]; }
  else if (idx < O_WHHT) { v = bih[idx - O_BIH]; }
  else if (idx < O_BHH)  {
    int p = idx - O_WHHT;
    if (p < 3072) {
      // FRAG_WIH: B-frags for gin @ Wih^T, K=32 (k<10 real). Two bf16 per slot.
      unsigned packed = 0;
#pragma unroll
      for (int h = 0; h < 2; ++h) {
        int e = 2 * p + h;
        int j = e & 7, L = (e >> 3) & 63, nt = e >> 9;
        int k = ((L >> 4) & 3) * 8 + j;
        float vv = (k < 10) ? Wih[(nt * 16 + (L & 15)) * 10 + k] : 0.f;
        unsigned us = (unsigned short)bf16r(vv);
        packed |= us << (16 * h);
      }
      ws[idx] = __builtin_bit_cast(float, packed);
      return;
    }
    int k = p / 192, o = p % 192;  v = Whh[o * 64 + k];
  }
  else if (idx < O_W4T)  { v = bhh[idx - O_BHH]; }
  else if (idx < O_B4)   {
    // R28: W4^T B-frags bf16-pair packed (K=64 in 2 frags, su pad 16).
    int p = idx - O_W4T;               // [0, 512)
    unsigned packed = 0;
#pragma unroll
    for (int h = 0; h < 2; ++h) {
      int e = 2 * p + h;               // [0, 1024)
      int j = e & 7, L = (e >> 3) & 63, s = e >> 9;
      int su = L & 15;
      int k = s * 32 + ((L >> 4) & 3) * 8 + j;
      float vv = (su < 8) ? W4[su * 64 + k] : 0.f;
      unsigned us = (unsigned short)bf16r(vv);
      packed |= us << (16 * h);
    }
    ws[idx] = __builtin_bit_cast(float, packed);
    return;
  }
  else if (idx < O_W3AT) { v = b4[idx - O_B4]; }
  else if (idx < O_B3A)  { int p = idx - O_W3AT; int k = p / 64, f = p % 64;    v = W3a[f * 8 + k]; }
  else if (idx < O_W3BT) { v = b3a[idx - O_B3A]; }
  else if (idx < O_B3B)  { int p = idx - O_W3BT; int k = p / 32, f = p % 32;    v = W3b[f * 64 + k]; }
  else if (idx < O_W3CT) { v = b3b[idx - O_B3B]; }
  else if (idx < O_B3C)  { int p = idx - O_W3CT; int k = p / 4, c = p % 4;      v = W3c[c * 32 + k]; }
  else if (idx < O_W1AT) { v = b3c[idx - O_B3C]; }
  else if (idx < O_B1A)  { int p = idx - O_W1AT; int c = p / 8, su = p % 8;     v = W1a[su * 3 + c]; }
  else                   { v = b1a[idx - O_B1A]; }
  ws[idx] = v;
}

// Layer-b K-step, parameterized (R21): packed fp32 math, bf16 MFMA pair.
// FH0 -> even out-cols (ACC0), FH1 -> odd out-cols (ACC1).
#define DO_STEP2(AROW, EWV, KOFF, Y0, Y1, W0, W1, FH0, FH1, ACC0, ACC1)        \
  {                                                                            \
    float4v x0 = *(const float4v*)&sA1[(AROW) * 68 + (KOFF)];                  \
    float4v x1 = *(const float4v*)&sA1[(AROW) * 68 + (KOFF) + 4];              \
    float4v z4 = {0.f, 0.f, 0.f, 0.f};                                         \
    float4v t0 = (x0 + Y0) + (EWV) * W0;                                       \
    float4v t1 = (x1 + Y1) + (EWV) * W1;                                       \
    t0 = __builtin_elementwise_max(t0, z4);                                    \
    t1 = __builtin_elementwise_max(t1, z4);                                    \
    short8 ahi;                                                                \
    ahi[0] = bf16r(t0.x); ahi[1] = bf16r(t0.y); ahi[2] = bf16r(t0.z);          \
    ahi[3] = bf16r(t0.w); ahi[4] = bf16r(t1.x); ahi[5] = bf16r(t1.y);          \
    ahi[6] = bf16r(t1.z); ahi[7] = bf16r(t1.w);                                \
    ACC0 = __builtin_amdgcn_mfma_f32_16x16x32_bf16(ahi, FH0, ACC0, 0, 0, 0);   \
    ACC1 = __builtin_amdgcn_mfma_f32_16x16x32_bf16(ahi, FH1, ACC1, 0, 0, 0);   \
  }

#define LAUNDER(v) __asm__ __volatile__("" : "+v"(v))

// (256,4): 4 waves/SIMD = 4 blocks/CU (LDS 38656). R30: byte-identical
// resubmit of R29 (dispatch 138.8-139.9 us = verified best; R29's bench
// 242.6 was an unlucky overhead draw: overhead term ranged 95.3-103.3 us
// across R24-R29 for the same measurement). All matmuls on MFMA; occupancy
// LDS-capped; register budget exactly consumed (5 spill incidents mapped);
// conflicts non-binding; in-wave pipelining redundant with TLP.
__global__ __launch_bounds__(256, 4) void gnn_fused(
    const float* __restrict__ read_gru_in,
    const float* __restrict__ gru_init,
    const float* __restrict__ feat,
    const float* __restrict__ edge_w,
    const float* __restrict__ noise_in,
    const float* __restrict__ xhat,
    const float* __restrict__ vep,
    const int* __restrict__ gnn_iter_p,
    const float* __restrict__ ws,
    const float* __restrict__ W4g,
    float* __restrict__ out)
{
  // spool: edge-phase {sA1, sA2, sM2} only (GRU handoff in registers since R24).
  __shared__ __attribute__((aligned(16))) char spool[23040];
  __shared__ __attribute__((aligned(16))) float sH[NN * 68];
  __shared__ float sNodes[NN * 9];
  __shared__ float sSum[NN * 8];
  __shared__ float sEw[ED];
  __shared__ float sC1[64];
  __shared__ float sWew[64];
  __shared__ float sX[NN];
  __shared__ float sV[NN];

  float* const sA1 = (float*)spool;                             // 8704 B
  float* const sA2 = (float*)(spool + 8704);                    // 8704 B
  __hip_bfloat16* const sM2 = (__hip_bfloat16*)(spool + 17408); // 5632 B

  const int b = blockIdx.x;
  const int t = threadIdx.x;
  const int lane = t & 63;
  const int wv = t >> 6;
  const int quad = lane >> 4;
  const int lm = lane & 15;

  const __hip_bfloat16* wb = (const __hip_bfloat16*)(ws + W_TOTAL2);

  // ---- per-sample inputs ----
  float noi = noise_in[b];
  for (int e = t; e < ED; e += 256) sEw[e] = edge_w[b * ED + e];
  if (t < NN) { sX[t] = xhat[b * NN + t]; sV[t] = vep[b * NN + t]; }
  if (t < 64) {
    sC1[t]  = ws[O_B2A + t] + noi * ws[O_W2AT + 17 * 64 + t];
    sWew[t] = ws[O_W2AT + 16 * 64 + t];
  }
#pragma unroll
  for (int i = 0; i < 8; ++i) {
    int p = t + 256 * i;
    sH[(p >> 6) * 68 + (p & 63)] = gru_init[b * (NN * HD) + p];
  }
  // ---- init_nodes (iteration 0 only) ----
  {
    const int git = gnn_iter_p[0];
    int n = t >> 3, su = t & 7;
    float acc;
    if (git == 0) {
      acc = ws[O_B1A + su];
#pragma unroll
      for (int c = 0; c < 3; ++c)
        acc += ws[O_W1AT + c * 8 + su] * feat[b * (NN * 3) + n * 3 + c];
    } else {
      acc = read_gru_in[b * (NN * SUD) + t];
    }
    sNodes[n * 9 + su] = acc;
  }
  __syncthreads();

  for (int it = 0; it < NITER; ++it) {
    // ---- edge-phase frag loads issued EARLY (hide L2 latency under A1/A2).
    //      Lifetime: here -> end of edge phase; does NOT span GRU phases. ----
    int ive = 0; LAUNDER(ive);
    const float* wsle = ws + ive;
    const __hip_bfloat16* wble = wb + ive;
    short8 fbh00 = *(const short8*)(wble + FRAG_B2 + (0 * 64 + lane) * 8);
    short8 fbh01 = *(const short8*)(wble + FRAG_B2 + (1 * 64 + lane) * 8);
    short8 fbh10 = *(const short8*)(wble + FRAG_B2 + (2 * 64 + lane) * 8);
    short8 fbh11 = *(const short8*)(wble + FRAG_B2 + (3 * 64 + lane) * 8);
    short8 fcf   = *(const short8*)(wble + FRAG_C + lane * 8);
    const float2v b2bv = *(const float2v*)&wsle[O_B2B + 2 * lm];
    const float   b2cl = wsle[O_B2C + lm];

    // ---- A1/A2 node projections via MFMA (K=8 real, zero-padded to 32).
    //      Wave wv computes f-cols [wv*16, wv*16+16) for both halves. ----
    {
      int iva = 0; LAUNDER(iva);
      const __hip_bfloat16* fp = wb + FRAG_A2P + iva;
      short8 aN[2];
#pragma unroll
      for (int mt = 0; mt < 2; ++mt) {
        short8 a = {0, 0, 0, 0, 0, 0, 0, 0};
        if (quad == 0) {
          const float* np = &sNodes[(mt * 16 + lm) * 9];
#pragma unroll
          for (int q = 0; q < 8; ++q) a[q] = bf16r(np[q]);
        }
        aN[mt] = a;
      }
      const int f = wv * 16 + lm;
      const float c1f = sC1[f];
#pragma unroll
      for (int half = 0; half < 2; ++half) {
        short8 bfr = *(const short8*)(fp + ((half * 4 + wv) * 64 + lane) * 8);
#pragma unroll
        for (int mt = 0; mt < 2; ++mt) {
          float4v acc = {0.f, 0.f, 0.f, 0.f};
          acc = __builtin_amdgcn_mfma_f32_16x16x32_bf16(aN[mt], bfr, acc, 0, 0, 0);
#pragma unroll
          for (int r = 0; r < 4; ++r) {
            int node = mt * 16 + quad * 4 + r;
            if (half == 0) sA1[node * 68 + f] = acc[r];
            else           sA2[node * 68 + f] = acc[r] + c1f;
          }
        }
      }
    }
    __syncthreads();

    // ---- edge MLP via MFMA (biases pre-folded into acc inits); tile1 compute
    //      pipelined into tile0's m2 store->read latency window (R21) ----
    {
      int ivz = 0; LAUNDER(ivz);
      __hip_bfloat16* m2w = sM2 + wv * (16 * 44);
      const int kq0 = quad * 8, kq1 = 32 + quad * 8;
      float4v wwA = *(const float4v*)&sWew[ivz + kq0];
      float4v wwB = *(const float4v*)&sWew[ivz + kq0 + 4];
      float4v wwC = *(const float4v*)&sWew[ivz + kq1];
      float4v wwD = *(const float4v*)&sWew[ivz + kq1 + 4];
      const float4v binit0 = {b2bv.x, b2bv.x, b2bv.x, b2bv.x};
      const float4v binit1 = {b2bv.y, b2bv.y, b2bv.y, b2bv.y};
      const float4v cinit  = {b2cl, b2cl, b2cl, b2cl};
      const int kkB = 16 + lm;
      const int kkB2 = (kkB < 31) ? kkB : 0;
      for (int ni = 0; ni < 8; ++ni) {
        const int jj = wv * 8 + ni;
        const int a0 = lm + (lm >= jj ? 1 : 0);
        const int a1 = kkB2 + (kkB2 >= jj ? 1 : 0);
        const float ew0 = sEw[ivz + jj * 31 + lm];
        const float ew1 = (kkB < 31) ? sEw[ivz + jj * 31 + kkB] : 0.f;
        float4v yA = *(const float4v*)&sA2[jj * 68 + kq0];
        float4v yB = *(const float4v*)&sA2[jj * 68 + kq0 + 4];
        float4v yC = *(const float4v*)&sA2[jj * 68 + kq1];
        float4v yD = *(const float4v*)&sA2[jj * 68 + kq1 + 4];
        // tile0 layer-b
        float4v acc00 = binit0;
        float4v acc01 = binit1;
        DO_STEP2(a0, ew0, kq0, yA, yB, wwA, wwB, fbh00, fbh10, acc00, acc01);
        DO_STEP2(a0, ew0, kq1, yC, yD, wwC, wwD, fbh01, fbh11, acc00, acc01);
        // tile0 m2 store
#pragma unroll
        for (int r = 0; r < 4; ++r) {
          float m20 = fmaxf(acc00[r], 0.f);
          float m21 = fmaxf(acc01[r], 0.f);
          ushort2 pp;
          pp.x = (unsigned short)bf16r(m20);
          pp.y = (unsigned short)bf16r(m21);
          *(ushort2*)(m2w + (quad * 4 + r) * 44 + 2 * lm) = pp;
        }
        // tile1 layer-b fills tile0's store->read latency window
        float4v acc10 = binit0;
        float4v acc11 = binit1;
        DO_STEP2(a1, ew1, kq0, yA, yB, wwA, wwB, fbh00, fbh10, acc10, acc11);
        DO_STEP2(a1, ew1, kq1, yC, yD, wwC, wwD, fbh01, fbh11, acc10, acc11);
        __asm__ __volatile__("" ::: "memory");
        // tile0 read + layer-c
        float psum;
        {
          short8 ac = *(const short8*)(m2w + lm * 44 + quad * 8);
          float4v c3 = cinit;
          c3 = __builtin_amdgcn_mfma_f32_16x16x32_bf16(ac, fcf, c3, 0, 0, 0);
          psum  = fmaxf(c3[0], 0.f);
          psum += fmaxf(c3[1], 0.f);
          psum += fmaxf(c3[2], 0.f);
          psum += fmaxf(c3[3], 0.f);
        }
        __asm__ __volatile__("" ::: "memory");
        // tile1 m2 store (after tile0 read)
#pragma unroll
        for (int r = 0; r < 4; ++r) {
          float m20 = fmaxf(acc10[r], 0.f);
          float m21 = fmaxf(acc11[r], 0.f);
          ushort2 pp;
          pp.x = (unsigned short)bf16r(m20);
          pp.y = (unsigned short)bf16r(m21);
          *(ushort2*)(m2w + (quad * 4 + r) * 44 + 2 * lm) = pp;
        }
        __asm__ __volatile__("" ::: "memory");
        // tile1 read + layer-c (kk=31 lane masked at r==3, quad==3)
        {
          short8 ac = *(const short8*)(m2w + lm * 44 + quad * 8);
          float4v c3 = cinit;
          c3 = __builtin_amdgcn_mfma_f32_16x16x32_bf16(ac, fcf, c3, 0, 0, 0);
#pragma unroll
          for (int r = 0; r < 4; ++r) {
            float v = fmaxf(c3[r], 0.f);
            if (r == 3) v = (quad == 3) ? 0.f : v;
            psum += v;
          }
        }
        __asm__ __volatile__("" ::: "memory");
        psum += __shfl_xor(psum, 16);
        psum += __shfl_xor(psum, 32);
        if (lane < 8) sSum[jj * 8 + lane] = psum;
      }
    }
    __syncthreads();

    // ---- GRU fused: gate pre-activations via MFMA, K=64 (H@Whh^T) plus
    //      K=32 gin=[sSum|x|v]@Wih^T. Wave wv owns gate tiles {wv,4+wv,8+wv};
    //      lane (quad,lm) holds node mt*16+quad*4+rr at col c = wv*16+lm
    //      (MFMA C-layout). No sGH round-trip, no GRU2 k-loop (R24). ----
    {
      int ivg = 0; LAUNDER(ivg);
      const __hip_bfloat16* wbl = wb + ivg;
      const __hip_bfloat16* wihf = (const __hip_bfloat16*)(ws + O_WHHT) + ivg;
      short8 aH[2][2];
      short8 aG[2];
#pragma unroll
      for (int mt = 0; mt < 2; ++mt) {
#pragma unroll
        for (int s = 0; s < 2; ++s) {
          const float* hp = &sH[(mt * 16 + lm) * 68 + s * 32 + quad * 8];
          float4v h0 = *(const float4v*)hp;
          float4v h1 = *(const float4v*)(hp + 4);
          short8 a;
          a[0] = bf16r(h0.x); a[1] = bf16r(h0.y); a[2] = bf16r(h0.z); a[3] = bf16r(h0.w);
          a[4] = bf16r(h1.x); a[5] = bf16r(h1.y); a[6] = bf16r(h1.z); a[7] = bf16r(h1.w);
          aH[mt][s] = a;
        }
        // gin A-frag: k = quad*8 + j ; k<8 -> sSum, k=8 -> x, k=9 -> v
        short8 g = {0, 0, 0, 0, 0, 0, 0, 0};
        int nrow = mt * 16 + lm;
        if (quad == 0) {
          float4v s0 = *(const float4v*)&sSum[nrow * 8];
          float4v s1 = *(const float4v*)&sSum[nrow * 8 + 4];
          g[0] = bf16r(s0.x); g[1] = bf16r(s0.y); g[2] = bf16r(s0.z); g[3] = bf16r(s0.w);
          g[4] = bf16r(s1.x); g[5] = bf16r(s1.y); g[6] = bf16r(s1.z); g[7] = bf16r(s1.w);
        } else if (quad == 1) {
          g[0] = bf16r(sX[nrow]);
          g[1] = bf16r(sV[nrow]);
        }
        aG[mt] = g;
      }
      const float4v zz4 = {0.f, 0.f, 0.f, 0.f};
      float4v pr0, pr1, pz0, pz1, phn0, phn1, pin0, pin1;
      {
        // r-gate tile (i+h merged)
        int gnt = wv;
        short8 bh0 = *(const short8*)(wbl + FRAG_WHH + ((gnt * 2 + 0) * 64 + lane) * 8);
        short8 bh1 = *(const short8*)(wbl + FRAG_WHH + ((gnt * 2 + 1) * 64 + lane) * 8);
        short8 bwi = *(const short8*)(wihf + (gnt * 64 + lane) * 8);
        pr0 = __builtin_amdgcn_mfma_f32_16x16x32_bf16(aG[0], bwi, zz4, 0, 0, 0);
        pr0 = __builtin_amdgcn_mfma_f32_16x16x32_bf16(aH[0][0], bh0, pr0, 0, 0, 0);
        pr0 = __builtin_amdgcn_mfma_f32_16x16x32_bf16(aH[0][1], bh1, pr0, 0, 0, 0);
        pr1 = __builtin_amdgcn_mfma_f32_16x16x32_bf16(aG[1], bwi, zz4, 0, 0, 0);
        pr1 = __builtin_amdgcn_mfma_f32_16x16x32_bf16(aH[1][0], bh0, pr1, 0, 0, 0);
        pr1 = __builtin_amdgcn_mfma_f32_16x16x32_bf16(aH[1][1], bh1, pr1, 0, 0, 0);
      }
      {
        // z-gate tile (i+h merged)
        int gnt = 4 + wv;
        short8 bh0 = *(const short8*)(wbl + FRAG_WHH + ((gnt * 2 + 0) * 64 + lane) * 8);
        short8 bh1 = *(const short8*)(wbl + FRAG_WHH + ((gnt * 2 + 1) * 64 + lane) * 8);
        short8 bwi = *(const short8*)(wihf + (gnt * 64 + lane) * 8);
        pz0 = __builtin_amdgcn_mfma_f32_16x16x32_bf16(aG[0], bwi, zz4, 0, 0, 0);
        pz0 = __builtin_amdgcn_mfma_f32_16x16x32_bf16(aH[0][0], bh0, pz0, 0, 0, 0);
        pz0 = __builtin_amdgcn_mfma_f32_16x16x32_bf16(aH[0][1], bh1, pz0, 0, 0, 0);
        pz1 = __builtin_amdgcn_mfma_f32_16x16x32_bf16(aG[1], bwi, zz4, 0, 0, 0);
        pz1 = __builtin_amdgcn_mfma_f32_16x16x32_bf16(aH[1][0], bh0, pz1, 0, 0, 0);
        pz1 = __builtin_amdgcn_mfma_f32_16x16x32_bf16(aH[1][1], bh1, pz1, 0, 0, 0);
      }
      {
        // n-gate tile: i and h kept SEPARATE (reference: tanh(i_n + r*h_n))
        int gnt = 8 + wv;
        short8 bh0 = *(const short8*)(wbl + FRAG_WHH + ((gnt * 2 + 0) * 64 + lane) * 8);
        short8 bh1 = *(const short8*)(wbl + FRAG_WHH + ((gnt * 2 + 1) * 64 + lane) * 8);
        short8 bwi = *(const short8*)(wihf + (gnt * 64 + lane) * 8);
        phn0 = __builtin_amdgcn_mfma_f32_16x16x32_bf16(aH[0][0], bh0, zz4, 0, 0, 0);
        phn0 = __builtin_amdgcn_mfma_f32_16x16x32_bf16(aH[0][1], bh1, phn0, 0, 0, 0);
        phn1 = __builtin_amdgcn_mfma_f32_16x16x32_bf16(aH[1][0], bh0, zz4, 0, 0, 0);
        phn1 = __builtin_amdgcn_mfma_f32_16x16x32_bf16(aH[1][1], bh1, phn1, 0, 0, 0);
        pin0 = __builtin_amdgcn_mfma_f32_16x16x32_bf16(aG[0], bwi, zz4, 0, 0, 0);
        pin1 = __builtin_amdgcn_mfma_f32_16x16x32_bf16(aG[1], bwi, zz4, 0, 0, 0);
      }
      // gates + blend, all register-resident; rcp-based sigmoid/tanh
      const int c = wv * 16 + lm;
      const float br  = ws[O_BIH + c]       + ws[O_BHH + c];
      const float bz  = ws[O_BIH + 64 + c]  + ws[O_BHH + 64 + c];
      const float bni = ws[O_BIH + 128 + c];
      const float bnh = ws[O_BHH + 128 + c];
      float4v hn0, hn1;
#pragma unroll
      for (int mt = 0; mt < 2; ++mt) {
#pragma unroll
        for (int rr = 0; rr < 4; ++rr) {
          int n = mt * 16 + quad * 4 + rr;
          float pre_r = ((mt == 0) ? pr0[rr]  : pr1[rr])  + br;
          float pre_z = ((mt == 0) ? pz0[rr]  : pz1[rr])  + bz;
          float i_n   = ((mt == 0) ? pin0[rr] : pin1[rr]) + bni;
          float h_n   = ((mt == 0) ? phn0[rr] : phn1[rr]) + bnh;
          float er = __expf(-pre_r);
          float r = __builtin_amdgcn_rcpf(1.f + er);
          float ez = __expf(-pre_z);
          float z = __builtin_amdgcn_rcpf(1.f + ez);
          float cd = i_n + r * h_n;
          float e2 = __expf(2.f * cd);
          float th = 1.f - 2.f * __builtin_amdgcn_rcpf(e2 + 1.f);
          float hv = sH[n * 68 + c];
          float hnew = th + z * (hv - th);
          if (mt == 0) hn0[rr] = hnew; else hn1[rr] = hnew;
        }
      }
      __syncthreads();   // all waves' sH reads (aH frags + blend hv) complete
#pragma unroll
      for (int rr = 0; rr < 4; ++rr) {
        sH[(quad * 4 + rr) * 68 + c]      = hn0[rr];
        sH[(16 + quad * 4 + rr) * 68 + c] = hn1[rr];
      }
    }
    __syncthreads();

    // ---- read_gru = W4 @ h + b4 -> sNodes.
    //      it<4 (R28): MFMA path (waves 0/1, mt 0/1); it==4: fp32 path. ----
    if (it < NITER - 1) {
      if (wv < 2) {
        int ivw = 0; LAUNDER(ivw);
        const __hip_bfloat16* w4f = (const __hip_bfloat16*)(ws + O_W4T) + ivw;
        const int mt = wv;
        short8 aW[2];
#pragma unroll
        for (int s = 0; s < 2; ++s) {
          const float* hp = &sH[(mt * 16 + lm) * 68 + s * 32 + quad * 8];
          float4v h0 = *(const float4v*)hp;
          float4v h1 = *(const float4v*)(hp + 4);
          short8 a;
          a[0] = bf16r(h0.x); a[1] = bf16r(h0.y); a[2] = bf16r(h0.z); a[3] = bf16r(h0.w);
          a[4] = bf16r(h1.x); a[5] = bf16r(h1.y); a[6] = bf16r(h1.z); a[7] = bf16r(h1.w);
          aW[s] = a;
        }
        short8 bW0 = *(const short8*)(w4f + (0 * 64 + lane) * 8);
        short8 bW1 = *(const short8*)(w4f + (1 * 64 + lane) * 8);
        const float b4l = (lm < 8) ? ws[O_B4 + lm] : 0.f;
        float4v acc = {b4l, b4l, b4l, b4l};
        acc = __builtin_amdgcn_mfma_f32_16x16x32_bf16(aW[0], bW0, acc, 0, 0, 0);
        acc = __builtin_amdgcn_mfma_f32_16x16x32_bf16(aW[1], bW1, acc, 0, 0, 0);
        if (lm < 8) {
#pragma unroll
          for (int rr = 0; rr < 4; ++rr)
            sNodes[(mt * 16 + quad * 4 + rr) * 9 + lm] = acc[rr];
        }
      }
    } else {
      int ivw = 0; LAUNDER(ivw);
      int n = t >> 3, su = t & 7;
      const float* w4r = W4g + ivw + su * 64;
      float4v acc4 = {0.f, 0.f, 0.f, 0.f};
#pragma unroll
      for (int k = 0; k < 64; k += 4) {
        float4v w = *(const float4v*)&w4r[k];
        float4v h = *(const float4v*)&sH[n * 68 + k];
        acc4 += w * h;
      }
      sNodes[n * 9 + su] = ws[O_B4 + su] + ((acc4.x + acc4.y) + (acc4.z + acc4.w));
    }
    __syncthreads();
  } // iterations

  // ---- head (R29): W3a via MFMA (K=8 pad 32), W3b via MFMA (K=64), W3c scalar ----
  {
    int ivh = 0; LAUNDER(ivh);
    const __hip_bfloat16* w3af = (const __hip_bfloat16*)(ws + O_WIHP) + ivh;
    short8 aN[2];
#pragma unroll
    for (int mt = 0; mt < 2; ++mt) {
      short8 a = {0, 0, 0, 0, 0, 0, 0, 0};
      if (quad == 0) {
        const float* np = &sNodes[(mt * 16 + lm) * 9];
#pragma unroll
        for (int q = 0; q < 8; ++q) a[q] = bf16r(np[q]);
      }
      aN[mt] = a;
    }
    const int f = wv * 16 + lm;
    const float b3af = ws[O_B3A + f];
    short8 bfr = *(const short8*)(w3af + (wv * 64 + lane) * 8);
#pragma unroll
    for (int mt = 0; mt < 2; ++mt) {
      float4v acc = {b3af, b3af, b3af, b3af};
      acc = __builtin_amdgcn_mfma_f32_16x16x32_bf16(aN[mt], bfr, acc, 0, 0, 0);
#pragma unroll
      for (int rr = 0; rr < 4; ++rr)
        sA1[(mt * 16 + quad * 4 + rr) * 68 + f] = acc[rr];
    }
  }
  __syncthreads();
  {
    int ivh = 0; LAUNDER(ivh);
    const __hip_bfloat16* w3bf = (const __hip_bfloat16*)(ws + O_WIHP + 1024) + ivh;
    const int mt = wv >> 1, ct = wv & 1;
    short8 aA[2];
#pragma unroll
    for (int s = 0; s < 2; ++s) {
      const float* ap = &sA1[(mt * 16 + lm) * 68 + s * 32 + quad * 8];
      float4v a0 = *(const float4v*)ap;
      float4v a1 = *(const float4v*)(ap + 4);
      short8 a;
      a[0] = bf16r(a0.x); a[1] = bf16r(a0.y); a[2] = bf16r(a0.z); a[3] = bf16r(a0.w);
      a[4] = bf16r(a1.x); a[5] = bf16r(a1.y); a[6] = bf16r(a1.z); a[7] = bf16r(a1.w);
      aA[s] = a;
    }
    short8 b0 = *(const short8*)(w3bf + ((ct * 2 + 0) * 64 + lane) * 8);
    short8 b1 = *(const short8*)(w3bf + ((ct * 2 + 1) * 64 + lane) * 8);
    const float b3bf = ws[O_B3B + ct * 16 + lm];
    float4v acc = {b3bf, b3bf, b3bf, b3bf};
    acc = __builtin_amdgcn_mfma_f32_16x16x32_bf16(aA[0], b0, acc, 0, 0, 0);
    acc = __builtin_amdgcn_mfma_f32_16x16x32_bf16(aA[1], b1, acc, 0, 0, 0);
#pragma unroll
    for (int rr = 0; rr < 4; ++rr)
      sA2[(mt * 16 + quad * 4 + rr) * 33 + ct * 16 + lm] = acc[rr];
  }
  __syncthreads();
  if (t < 128) {
    int n = t >> 2, c = t & 3;
    float acc = ws[O_B3C + c];
#pragma unroll
    for (int k = 0; k < 32; ++k) acc += ws[O_W3CT + k * 4 + c] * sA2[n * 33 + k];
    out[b * (NN * NCD) + t] = acc;
  }
  out[BB * NN * NCD + b * (NN * SUD) + t] = sNodes[(t >> 3) * 9 + (t & 7)];
#pragma unroll
  for (int i = 0; i < 8; ++i) {
    int p = t + 256 * i;
    out[BB * NN * NCD + BB * NN * SUD + b * (NN * HD) + p] =
        sH[(p >> 6) * 68 + (p & 63)];
  }
}

extern "C" void kernel_launch(void* const* d_in, const int* in_sizes, int n_in,
                              void* d_out, int out_size, void* d_ws, size_t ws_size,
                              hipStream_t stream) {
  typedef const float* F32;
  F32 read_gru = (F32)d_in[0];
  F32 gru_init = (F32)d_in[1];
  F32 feat     = (F32)d_in[2];
  F32 edge_w   = (F32)d_in[3];
  F32 noise    = (F32)d_in[4];
  F32 xh       = (F32)d_in[5];
  F32 vp       = (F32)d_in[6];
  F32 W1a = (F32)d_in[7];  F32 b1a = (F32)d_in[8];
  F32 W2a = (F32)d_in[9];  F32 b2a = (F32)d_in[10];
  F32 W2b = (F32)d_in[11]; F32 b2b = (F32)d_in[12];
  F32 W2c = (F32)d_in[13]; F32 b2c = (F32)d_in[14];
  F32 Wih = (F32)d_in[15]; F32 bih = (F32)d_in[16];
  F32 Whh = (F32)d_in[17]; F32 bhh = (F32)d_in[18];
  F32 W3a = (F32)d_in[19]; F32 b3a = (F32)d_in[20];
  F32 W3b = (F32)d_in[21]; F32 b3b = (F32)d_in[22];
  F32 W3c = (F32)d_in[23]; F32 b3c = (F32)d_in[24];
  F32 W4  = (F32)d_in[25]; F32 b4  = (F32)d_in[26];
  const int* git = (const int*)d_in[27];
  float* ws = (float*)d_ws;   // needs 139,216 B

  prep_weights<<<(PREP_TOTAL + 255) / 256, 256, 0, stream>>>(
      W2a, b2a, W2b, b2b, W2c, b2c, Wih, bih, Whh, bhh,
      W3a, b3a, W3b, b3b, W3c, b3c, W4, b4, W1a, b1a, ws);

  gnn_fused<<<BB, 256, 0, stream>>>(read_gru, gru_init, feat, edge_w, noise,
                                    xh, vp, git, ws, W4, (float*)d_out);
}